// Round 6
// baseline (41.051 us; speedup 1.0000x reference)
//
#include <hip/hip_runtime.h>

// Jacobi damped smoother: out = x + (w/k11) * (f - conv3x3(x, k)), zero padding.
// B=64, H=512, W=512, fp32.
// R4 structure (ROWS=2, shfl halos, 16384 waves) + nontemporal stores.
// Isolating NT-store effect: out (64 MB, never read) should not allocate in
// L2/L3, leaving the 256 MB Infinity Cache for x+f (128 MB) -> FETCH collapses.

#define ROWS 2

typedef float f32x4 __attribute__((ext_vector_type(4)));

__global__ __launch_bounds__(256) void jacobi_kernel(
    const float* __restrict__ x,
    const float* __restrict__ f,
    const float* __restrict__ kA,
    float* __restrict__ out)
{
    const int tid  = blockIdx.x * blockDim.x + threadIdx.x;
    const int lane = tid & 63;
    const int wid  = tid >> 6;
    const int strip = wid & 255;        // 512 / ROWS = 256 strips per batch
    const int b     = wid >> 8;
    const int r0    = strip * ROWS;
    const int c0    = lane << 3;        // 8 columns per lane

    // per-batch 3x3 kernel (uniform across the wave -> scalar broadcast)
    const float* kb = kA + b * 9;
    const float k00 = kb[0], k01 = kb[1], k02 = kb[2];
    const float k10 = kb[3], k11 = kb[4], k12 = kb[5];
    const float k20 = kb[6], k21 = kb[7], k22 = kb[8];
    const float weight = (2.0f / 3.0f) / k11;

    const size_t plane = (size_t)b << 18;       // 512*512
    const float* xb = x + plane;
    const float* fb = f + plane + ((size_t)r0 << 9) + c0;
    float*       ob = out + plane + ((size_t)r0 << 9) + c0;

    // ---- load ROWS+2 x-rows, 8 wide + 2 halo slots each (all static indexing) ----
    float xr[ROWS + 2][10];
    #pragma unroll
    for (int q = 0; q < ROWS + 2; ++q) {
        const int r = r0 - 1 + q;               // wave-uniform validity
        if (r >= 0 && r < 512) {
            const float* p = xb + ((size_t)r << 9) + c0;
            const f32x4 a = *(const f32x4*)p;
            const f32x4 c = *(const f32x4*)(p + 4);
            xr[q][1] = a.x; xr[q][2] = a.y; xr[q][3] = a.z; xr[q][4] = a.w;
            xr[q][5] = c.x; xr[q][6] = c.y; xr[q][7] = c.z; xr[q][8] = c.w;
        } else {
            #pragma unroll
            for (int c2 = 1; c2 < 9; ++c2) xr[q][c2] = 0.0f;
        }
    }

    // ---- halos via cross-lane shuffle (wave spans the full row) ----
    #pragma unroll
    for (int q = 0; q < ROWS + 2; ++q) {
        float left  = __shfl_up(xr[q][8], 1);
        float right = __shfl_down(xr[q][1], 1);
        xr[q][0] = (lane == 0)  ? 0.0f : left;   // image left edge -> 0
        xr[q][9] = (lane == 63) ? 0.0f : right;  // image right edge -> 0
    }

    // ---- per output row: load f, stencil, nontemporal store ----
    #pragma unroll
    for (int rr = 0; rr < ROWS; ++rr) {
        const float* fp = fb + ((size_t)rr << 9);
        const f32x4 f0 = *(const f32x4*)fp;
        const f32x4 f1 = *(const f32x4*)(fp + 4);
        const float fx[8] = { f0.x, f0.y, f0.z, f0.w, f1.x, f1.y, f1.z, f1.w };

        float res[8];
        #pragma unroll
        for (int p = 0; p < 8; ++p) {
            float Ax = k00 * xr[rr][p]     + k01 * xr[rr][p + 1]     + k02 * xr[rr][p + 2]
                     + k10 * xr[rr + 1][p] + k11 * xr[rr + 1][p + 1] + k12 * xr[rr + 1][p + 2]
                     + k20 * xr[rr + 2][p] + k21 * xr[rr + 2][p + 1] + k22 * xr[rr + 2][p + 2];
            res[p] = xr[rr + 1][p + 1] + weight * (fx[p] - Ax);
        }

        float* op = ob + ((size_t)rr << 9);
        f32x4 v0 = { res[0], res[1], res[2], res[3] };
        f32x4 v1 = { res[4], res[5], res[6], res[7] };
        __builtin_nontemporal_store(v0, (f32x4*)op);
        __builtin_nontemporal_store(v1, (f32x4*)(op + 4));
    }
}

extern "C" void kernel_launch(void* const* d_in, const int* in_sizes, int n_in,
                              void* d_out, int out_size, void* d_ws, size_t ws_size,
                              hipStream_t stream) {
    const float* x  = (const float*)d_in[0];
    const float* f  = (const float*)d_in[1];
    const float* kA = (const float*)d_in[2];
    float* out = (float*)d_out;

    // waves = 64 batches * 256 strips = 16384 ; threads = 1048576 ; blocks = 4096
    const int total = 64 * (512 / ROWS) * 64;
    const int block = 256;
    const int grid  = total / block;
    jacobi_kernel<<<grid, block, 0, stream>>>(x, f, kA, out);
}

// Round 7
// 36.162 us; speedup vs baseline: 1.1352x; 1.1352x over previous
//
#include <hip/hip_runtime.h>

// Jacobi damped smoother: out = x + (w/k11) * (f - conv3x3(x, k)), zero padding.
// B=64, H=512, W=512, fp32.
// One wave covers a full 512-col row (8 cols/lane); halos via shfl, not memory.
// ROWS=2 rows per wave, 16384 waves. All 12 VMEM loads (4 x-rows + 2 f-rows,
// vec4 pairs) issued upfront for max MLP before the shfl/compute chain.
// Normal cached stores (NT stores measured +34% WRITE_SIZE on gfx950 — R6).

#define ROWS 2

typedef float f32x4 __attribute__((ext_vector_type(4)));

__global__ __launch_bounds__(256) void jacobi_kernel(
    const float* __restrict__ x,
    const float* __restrict__ f,
    const float* __restrict__ kA,
    float* __restrict__ out)
{
    const int tid  = blockIdx.x * blockDim.x + threadIdx.x;
    const int lane = tid & 63;
    const int wid  = tid >> 6;
    const int strip = wid & 255;        // 512 / ROWS = 256 strips per batch
    const int b     = wid >> 8;
    const int r0    = strip * ROWS;
    const int c0    = lane << 3;        // 8 columns per lane

    const size_t plane = (size_t)b << 18;       // 512*512
    const float* xb = x + plane;
    const float* fb = f + plane + ((size_t)r0 << 9) + c0;
    float*       ob = out + plane + ((size_t)r0 << 9) + c0;

    // ---- issue ALL loads upfront: 4 x-rows + 2 f-rows, vec4 pairs ----
    f32x4 xa[ROWS + 2], xc[ROWS + 2];
    #pragma unroll
    for (int q = 0; q < ROWS + 2; ++q) {
        const int r = r0 - 1 + q;               // wave-uniform validity
        if (r >= 0 && r < 512) {
            const float* p = xb + ((size_t)r << 9) + c0;
            xa[q] = *(const f32x4*)p;
            xc[q] = *(const f32x4*)(p + 4);
        } else {
            xa[q] = (f32x4){0.0f, 0.0f, 0.0f, 0.0f};
            xc[q] = (f32x4){0.0f, 0.0f, 0.0f, 0.0f};
        }
    }
    f32x4 fv[2 * ROWS];
    #pragma unroll
    for (int rr = 0; rr < ROWS; ++rr) {
        const float* fp = fb + ((size_t)rr << 9);
        fv[2 * rr]     = *(const f32x4*)fp;
        fv[2 * rr + 1] = *(const f32x4*)(fp + 4);
    }

    // per-batch 3x3 kernel (uniform across the wave -> scalar broadcast)
    const float* kb = kA + b * 9;
    const float k00 = kb[0], k01 = kb[1], k02 = kb[2];
    const float k10 = kb[3], k11 = kb[4], k12 = kb[5];
    const float k20 = kb[6], k21 = kb[7], k22 = kb[8];
    const float weight = (2.0f / 3.0f) / k11;

    // ---- unpack + halos via cross-lane shuffle (wave spans the full row) ----
    float xr[ROWS + 2][10];
    #pragma unroll
    for (int q = 0; q < ROWS + 2; ++q) {
        xr[q][1] = xa[q].x; xr[q][2] = xa[q].y; xr[q][3] = xa[q].z; xr[q][4] = xa[q].w;
        xr[q][5] = xc[q].x; xr[q][6] = xc[q].y; xr[q][7] = xc[q].z; xr[q][8] = xc[q].w;
        float left  = __shfl_up(xr[q][8], 1);
        float right = __shfl_down(xr[q][1], 1);
        xr[q][0] = (lane == 0)  ? 0.0f : left;   // image left edge -> 0
        xr[q][9] = (lane == 63) ? 0.0f : right;  // image right edge -> 0
    }

    // ---- per output row: stencil, store ----
    #pragma unroll
    for (int rr = 0; rr < ROWS; ++rr) {
        const float fx[8] = { fv[2*rr].x, fv[2*rr].y, fv[2*rr].z, fv[2*rr].w,
                              fv[2*rr+1].x, fv[2*rr+1].y, fv[2*rr+1].z, fv[2*rr+1].w };

        float res[8];
        #pragma unroll
        for (int p = 0; p < 8; ++p) {
            float Ax = k00 * xr[rr][p]     + k01 * xr[rr][p + 1]     + k02 * xr[rr][p + 2]
                     + k10 * xr[rr + 1][p] + k11 * xr[rr + 1][p + 1] + k12 * xr[rr + 1][p + 2]
                     + k20 * xr[rr + 2][p] + k21 * xr[rr + 2][p + 1] + k22 * xr[rr + 2][p + 2];
            res[p] = xr[rr + 1][p + 1] + weight * (fx[p] - Ax);
        }

        float* op = ob + ((size_t)rr << 9);
        f32x4 v0 = { res[0], res[1], res[2], res[3] };
        f32x4 v1 = { res[4], res[5], res[6], res[7] };
        *(f32x4*)op       = v0;
        *(f32x4*)(op + 4) = v1;
    }
}

extern "C" void kernel_launch(void* const* d_in, const int* in_sizes, int n_in,
                              void* d_out, int out_size, void* d_ws, size_t ws_size,
                              hipStream_t stream) {
    const float* x  = (const float*)d_in[0];
    const float* f  = (const float*)d_in[1];
    const float* kA = (const float*)d_in[2];
    float* out = (float*)d_out;

    // waves = 64 batches * 256 strips = 16384 ; threads = 1048576 ; blocks = 4096
    const int total = 64 * (512 / ROWS) * 64;
    const int block = 256;
    const int grid  = total / block;
    jacobi_kernel<<<grid, block, 0, stream>>>(x, f, kA, out);
}

// Round 8
// 35.627 us; speedup vs baseline: 1.1522x; 1.0150x over previous
//
#include <hip/hip_runtime.h>

// Jacobi damped smoother: out = x + (w/k11) * (f - conv3x3(x, k)), zero padding.
// B=64, H=512, W=512, fp32.
// One wave covers a full 512-col row (8 cols/lane); halos via shfl, not memory.
// ROWS=4 rows per wave -> x logical reads 1.5x (vs 2x at ROWS=2): testing the
// aggregate-memory-BW model (duration ~ logical traffic incl. L2/L3 re-reads).
// All loads hoisted upfront for MLP. Normal cached stores (NT measured +34%
// WRITE_SIZE on gfx950 — R6).

#define ROWS 4

typedef float f32x4 __attribute__((ext_vector_type(4)));

__global__ __launch_bounds__(256) void jacobi_kernel(
    const float* __restrict__ x,
    const float* __restrict__ f,
    const float* __restrict__ kA,
    float* __restrict__ out)
{
    const int tid  = blockIdx.x * blockDim.x + threadIdx.x;
    const int lane = tid & 63;
    const int wid  = tid >> 6;
    const int strip = wid & 127;        // 512 / ROWS = 128 strips per batch
    const int b     = wid >> 7;
    const int r0    = strip * ROWS;
    const int c0    = lane << 3;        // 8 columns per lane

    const size_t plane = (size_t)b << 18;       // 512*512
    const float* xb = x + plane;
    const float* fb = f + plane + ((size_t)r0 << 9) + c0;
    float*       ob = out + plane + ((size_t)r0 << 9) + c0;

    // ---- issue ALL loads upfront: 6 x-rows + 4 f-rows, vec4 pairs ----
    f32x4 xa[ROWS + 2], xc[ROWS + 2];
    #pragma unroll
    for (int q = 0; q < ROWS + 2; ++q) {
        const int r = r0 - 1 + q;               // wave-uniform validity
        if (r >= 0 && r < 512) {
            const float* p = xb + ((size_t)r << 9) + c0;
            xa[q] = *(const f32x4*)p;
            xc[q] = *(const f32x4*)(p + 4);
        } else {
            xa[q] = (f32x4){0.0f, 0.0f, 0.0f, 0.0f};
            xc[q] = (f32x4){0.0f, 0.0f, 0.0f, 0.0f};
        }
    }
    f32x4 fv[2 * ROWS];
    #pragma unroll
    for (int rr = 0; rr < ROWS; ++rr) {
        const float* fp = fb + ((size_t)rr << 9);
        fv[2 * rr]     = *(const f32x4*)fp;
        fv[2 * rr + 1] = *(const f32x4*)(fp + 4);
    }

    // per-batch 3x3 kernel (uniform across the wave -> scalar broadcast)
    const float* kb = kA + b * 9;
    const float k00 = kb[0], k01 = kb[1], k02 = kb[2];
    const float k10 = kb[3], k11 = kb[4], k12 = kb[5];
    const float k20 = kb[6], k21 = kb[7], k22 = kb[8];
    const float weight = (2.0f / 3.0f) / k11;

    // ---- unpack + halos via cross-lane shuffle (wave spans the full row) ----
    float xr[ROWS + 2][10];
    #pragma unroll
    for (int q = 0; q < ROWS + 2; ++q) {
        xr[q][1] = xa[q].x; xr[q][2] = xa[q].y; xr[q][3] = xa[q].z; xr[q][4] = xa[q].w;
        xr[q][5] = xc[q].x; xr[q][6] = xc[q].y; xr[q][7] = xc[q].z; xr[q][8] = xc[q].w;
        float left  = __shfl_up(xr[q][8], 1);
        float right = __shfl_down(xr[q][1], 1);
        xr[q][0] = (lane == 0)  ? 0.0f : left;   // image left edge -> 0
        xr[q][9] = (lane == 63) ? 0.0f : right;  // image right edge -> 0
    }

    // ---- per output row: stencil, store ----
    #pragma unroll
    for (int rr = 0; rr < ROWS; ++rr) {
        const float fx[8] = { fv[2*rr].x, fv[2*rr].y, fv[2*rr].z, fv[2*rr].w,
                              fv[2*rr+1].x, fv[2*rr+1].y, fv[2*rr+1].z, fv[2*rr+1].w };

        float res[8];
        #pragma unroll
        for (int p = 0; p < 8; ++p) {
            float Ax = k00 * xr[rr][p]     + k01 * xr[rr][p + 1]     + k02 * xr[rr][p + 2]
                     + k10 * xr[rr + 1][p] + k11 * xr[rr + 1][p + 1] + k12 * xr[rr + 1][p + 2]
                     + k20 * xr[rr + 2][p] + k21 * xr[rr + 2][p + 1] + k22 * xr[rr + 2][p + 2];
            res[p] = xr[rr + 1][p + 1] + weight * (fx[p] - Ax);
        }

        float* op = ob + ((size_t)rr << 9);
        f32x4 v0 = { res[0], res[1], res[2], res[3] };
        f32x4 v1 = { res[4], res[5], res[6], res[7] };
        *(f32x4*)op       = v0;
        *(f32x4*)(op + 4) = v1;
    }
}

extern "C" void kernel_launch(void* const* d_in, const int* in_sizes, int n_in,
                              void* d_out, int out_size, void* d_ws, size_t ws_size,
                              hipStream_t stream) {
    const float* x  = (const float*)d_in[0];
    const float* f  = (const float*)d_in[1];
    const float* kA = (const float*)d_in[2];
    float* out = (float*)d_out;

    // waves = 64 batches * 128 strips = 8192 ; threads = 524288 ; blocks = 2048
    const int total = 64 * (512 / ROWS) * 64;
    const int block = 256;
    const int grid  = total / block;
    jacobi_kernel<<<grid, block, 0, stream>>>(x, f, kA, out);
}